// Round 2
// baseline (234.322 us; speedup 1.0000x reference)
//
#include <hip/hip_runtime.h>
#include <hip/hip_bf16.h>

typedef __bf16 bf16;
typedef __attribute__((ext_vector_type(8))) __bf16 bf16x8;
typedef __attribute__((ext_vector_type(4))) float floatx4;

#define NPART 16   // scores n-blocks per row (S/128)
#define NSLOT 32   // NPART * 2 wave-halves: each wave gets a private slot (no atomics, no races)

// async global->LDS, 16B per lane. LDS dest is wave-uniform base + lane*16 (fixed by HW);
// we swizzle the GLOBAL source chunk so LDS frag reads are conflict-free (R5: conflicts 4.2M -> 0).
__device__ __forceinline__ void gl_lds16(const bf16* g, bf16* l) {
    __builtin_amdgcn_global_load_lds(
        (const __attribute__((address_space(1))) unsigned int*)g,
        (__attribute__((address_space(3))) unsigned int*)l,
        16, 0, 0);
}

// 4(m) x 2(n) supertile swizzle: consecutive dispatch ids share A/B bands (L2 locality).
// Requires gridDim.x % 4 == 0 and gridDim.y % 2 == 0. Bijective on the grid.
__device__ __forceinline__ void swizzle_mn(int& bm, int& bn) {
    int gx = gridDim.x;
    int f  = blockIdx.y * gx + blockIdx.x;
    int st = f >> 3, r = f & 7;
    int mgroups = gx >> 2;
    bm = (st % mgroups) * 4 + (r & 3);
    bn = (st / mgroups) * 2 + (r >> 2);
}

// ---------------------------------------------------------------- x fp32 [R,C] -> xb bf16 [R,C] AND xt bf16 [C,R]
__global__ __launch_bounds__(256) void cast_both(const float* __restrict__ in,
                                                 bf16* __restrict__ outn,
                                                 bf16* __restrict__ outt,
                                                 int R, int C) {
    __shared__ float tile[32][33];
    const long long bz = blockIdx.z;
    in   += bz * (long long)R * C;
    outn += bz * (long long)R * C;
    outt += bz * (long long)R * C;
    const int r0 = blockIdx.x * 32, c0 = blockIdx.y * 32;
    const int tx = threadIdx.x & 31, ty = threadIdx.x >> 5;
#pragma unroll
    for (int i = 0; i < 32; i += 8) {
        float v = in[(long long)(r0 + ty + i) * C + (c0 + tx)];
        tile[ty + i][tx] = v;
        outn[(long long)(r0 + ty + i) * C + (c0 + tx)] = (bf16)v;
    }
    __syncthreads();
#pragma unroll
    for (int i = 0; i < 32; i += 8)
        outt[(long long)(c0 + ty + i) * R + (r0 + tx)] = (bf16)tile[tx][ty + i];
}

// ---------------------------------------------------------------- fp32 [R,C] -> bf16 [C,R] (for W)
__global__ __launch_bounds__(256) void cast_transpose(const float* __restrict__ in,
                                                      bf16* __restrict__ out,
                                                      int R, int C) {
    __shared__ float tile[32][33];
    const int r0 = blockIdx.x * 32, c0 = blockIdx.y * 32;
    const int tx = threadIdx.x & 31, ty = threadIdx.x >> 5;
#pragma unroll
    for (int i = 0; i < 32; i += 8)
        tile[ty + i][tx] = in[(long long)(r0 + ty + i) * C + (c0 + tx)];
    __syncthreads();
#pragma unroll
    for (int i = 0; i < 32; i += 8)
        out[(long long)(c0 + ty + i) * R + (r0 + tx)] = (bf16)tile[tx][ty + i];
}

// tanh via one exp + one rcp; exact saturation at +-1. (R7: poly outer-exp regressed; keep __expf.)
__device__ __forceinline__ float fast_tanh(float v) {
    float e = __expf(2.0f * v);
    return 1.0f - 2.0f / (e + 1.0f);
}

// ---------------------------------------------------------------- 256(M)x128(N) tile, BK=64, NT GEMM
// R10: counted-vmcnt pipeline (catalog T3+T4). 3 LDS buffers, depth-2 prefetch, raw s_barrier +
// s_waitcnt vmcnt(6) in steady state (NEVER a full drain inside the K-loop; that drain was the
// 2-phase ceiling at ~480 TF / 19.5% MfmaUtil in R9).
// Invariants (correctness):
//   * per-wave VMEM retires FIFO: after stage(kt+2) is issued, vmcnt(6) retires exactly the 6
//     loads of tile kt+1; the s_barrier makes it collective -> tile kt+1's LDS is complete.
//   * stage(kt+2) overwrites buf[(kt+2)%3] == buf[(kt-1)%3]; every wave's ds_reads of tile kt-1
//     were dataflow-consumed by its MFMAs before the previous barrier -> no read-under-write.
//   * last 2 tiles: no further stage, single vmcnt(0) at iteration NT-2 only.
// 8 waves (512 thr), wave grid 4(M)x2(N), per-wave 64x64 output, 32 MFMA/K-step, acc 64 VGPR.
// LDS = 3*(32+16) KB + 1 KB = 145 KB -> 1 block/CU (8 waves resident).
// T5 setprio around each 16-MFMA cluster (pays only on phase-split schedules -> this one).
// MODE 1 (scores): store bf16 exp(tanh(v)); per-(row, n-block, wave-half) rowsum partials.
// MODE 2 (PV):     prologue reduces NSLOT partials per row; store fp32 v * invRowsum.
template <int MODE>
__global__ __launch_bounds__(512) void gemm256(const bf16* __restrict__ A,
                                               const bf16* __restrict__ Bm,
                                               void* __restrict__ Cout,
                                               float* __restrict__ rpart,
                                               int M, int N, int K,
                                               long long batchA, long long batchB,
                                               long long batchC, long long batchR) {
    const long long bz = blockIdx.z;
    A  += bz * batchA;
    Bm += bz * batchB;

    __shared__ bf16 As[3][256 * 64];   // 3 x 32 KB
    __shared__ bf16 Bs[3][128 * 64];   // 3 x 16 KB
    __shared__ float rs[256];          // MODE 2 only

    const int t    = threadIdx.x;      // 0..511
    const int lane = t & 63;
    const int wid  = t >> 6;           // 0..7
    const int quad = lane >> 4;
    const int l16  = lane & 15;
    const int wr   = wid >> 1;         // 0..3 : M block of 64
    const int wc   = wid & 1;          // 0..1 : N block of 64

    int bm, bn;
    swizzle_mn(bm, bn);
    const int m0 = bm * 256;
    const int n0 = bn * 128;

    floatx4 acc[4][4] = {};

    // staging: LDS slot (r, chunk c) holds global chunk c ^ (r&7); swizzle folded into src pointer.
    const int ra  = t >> 3;                       // 0..63
    const int ca8 = (((t & 7) ^ (ra & 7))) * 8;
    const long long rstep = 64LL * K;
    const bf16* Abase = A + (long long)(m0 + ra) * K + ca8;
    const bf16* Bbase = Bm + (long long)(n0 + ra) * K + ca8;

    // MODE 2: fold softmax denominators first (these 8 VMEM loads retire under a compiler wait
    // BEFORE any staging is issued, and they are older than all stage loads -> FIFO counting of
    // the manual vmcnt(6) below stays exact either way).
    if (MODE == 2) {
        if (t < 256) {
            const float* pp = rpart + (bz * batchR + m0 + t) * NSLOT;
            float s = 0.f;
#pragma unroll
            for (int c = 0; c < NSLOT / 4; ++c) {
                float4 p = ((const float4*)pp)[c];
                s += (p.x + p.y) + (p.z + p.w);
            }
            rs[t] = 1.0f / s;
        }
        // rs written before first barrier; read only after the K-loop -> ordering safe
    }

    const int NT = K >> 6;             // >= 2 always (K=512 or 2048)

    auto stage = [&](int buf, int kt) {   // 6 VMEM ops/thread: A 4 rounds, B 2 rounds
        const long long k0 = (long long)kt * 64;
#pragma unroll
        for (int i = 0; i < 4; ++i)
            gl_lds16(Abase + k0 + i * rstep, &As[buf][(t + 512 * i) * 8]);
#pragma unroll
        for (int i = 0; i < 2; ++i)
            gl_lds16(Bbase + k0 + i * rstep, &Bs[buf][(t + 512 * i) * 8]);
    };

    auto compute = [&](int buf) {
#pragma unroll
        for (int s = 0; s < 2; ++s) {
            const int cq = ((s * 4 + quad) ^ (l16 & 7)) * 8;
            bf16x8 af[4], bfr[4];
#pragma unroll
            for (int i = 0; i < 4; ++i)
                af[i] = *(const bf16x8*)(&As[buf][(wr * 64 + i * 16 + l16) * 64 + cq]);
#pragma unroll
            for (int j = 0; j < 4; ++j)
                bfr[j] = *(const bf16x8*)(&Bs[buf][(wc * 64 + j * 16 + l16) * 64 + cq]);
            __builtin_amdgcn_s_setprio(1);
#pragma unroll
            for (int i = 0; i < 4; ++i)
#pragma unroll
                for (int j = 0; j < 4; ++j)
                    acc[i][j] = __builtin_amdgcn_mfma_f32_16x16x32_bf16(af[i], bfr[j], acc[i][j], 0, 0, 0);
            __builtin_amdgcn_s_setprio(0);
        }
    };

    // prologue: 2 tiles in flight, wait only for tile 0 (12 outstanding -> 6)
    stage(0, 0);
    stage(1, 1);
    asm volatile("s_waitcnt vmcnt(6)\n\ts_barrier" ::: "memory");

    for (int kt = 0; kt < NT - 1; ++kt) {
        if (kt + 2 < NT) {
            stage((kt + 2) % 3, kt + 2);   // issue first: longest time in flight
            compute(kt % 3);
            asm volatile("s_waitcnt vmcnt(6)\n\ts_barrier" ::: "memory");   // tile kt+1 ready
        } else {
            compute(kt % 3);
            asm volatile("s_waitcnt vmcnt(0)\n\ts_barrier" ::: "memory");   // final tile ready
        }
    }
    compute((NT - 1) % 3);

    if (MODE == 1) {
        bf16* Cg = (bf16*)Cout + bz * batchC;
        const int slot = bn * 2 + wc;   // private slot per (n-block, wave-half)
#pragma unroll
        for (int i = 0; i < 4; ++i)
#pragma unroll
            for (int r = 0; r < 4; ++r) {
                long long row = m0 + wr * 64 + i * 16 + quad * 4 + r;
                float s = 0.f;
#pragma unroll
                for (int j = 0; j < 4; ++j) {
                    float v = __expf(fast_tanh(acc[i][j][r]));
                    s += v;
                    Cg[row * (long long)N + (n0 + wc * 64 + j * 16 + l16)] = (bf16)v;
                }
#pragma unroll
                for (int msk = 1; msk < 16; msk <<= 1) s += __shfl_xor(s, msk);
                if (l16 == 0)
                    rpart[(bz * batchR + row) * NSLOT + slot] = s;   // plain store, race-free
            }
    } else {
        float* Og = (float*)Cout + bz * batchC;
#pragma unroll
        for (int i = 0; i < 4; ++i)
#pragma unroll
            for (int r = 0; r < 4; ++r) {
                int rl = wr * 64 + i * 16 + quad * 4 + r;
                float inv = rs[rl];
                long long row = m0 + rl;
#pragma unroll
                for (int j = 0; j < 4; ++j)
                    Og[row * (long long)N + (n0 + wc * 64 + j * 16 + l16)] = acc[i][j][r] * inv;
            }
    }
}

// ---------------------------------------------------------------- 64(M)x128(N) tile, BK=64, NT (proj)
// R9: double-buffered single-barrier 2-phase K-loop (small kernel, ~8% of total; left as-is in R10).
__global__ __launch_bounds__(256) void gemm64_nt(const bf16* __restrict__ A,
                                                 const bf16* __restrict__ Bm,
                                                 bf16* __restrict__ Cout,
                                                 int M, int N, int K) {
    __shared__ bf16 As[2][64 * 64];    // 2 x 8 KB
    __shared__ bf16 Bs[2][128 * 64];   // 2 x 16 KB

    const int t    = threadIdx.x;
    const int lane = t & 63;
    const int wave = t >> 6;
    const int quad = lane >> 4;
    const int l16  = lane & 15;

    const int m0 = blockIdx.x * 64;
    const int n0 = blockIdx.y * 128;
    const int wn = wave * 32;

    floatx4 acc[4][2] = {};

    const int ra = t >> 3;
    const int ca = (((t & 7) ^ (ra & 7))) * 8;
    const long long rstep = 32LL * K;
    const bf16* Abase = A + (long long)(m0 + ra) * K + ca;
    const bf16* Bbase = Bm + (long long)(n0 + ra) * K + ca;

    const int cq0 = ((quad) ^ (l16 & 7)) * 8;
    const int cq1 = ((4 + quad) ^ (l16 & 7)) * 8;

    auto stage = [&](int buf, int k0) {
#pragma unroll
        for (int i = 0; i < 2; ++i)
            gl_lds16(Abase + k0 + i * rstep, &As[buf][(t + 256 * i) * 8]);
#pragma unroll
        for (int i = 0; i < 4; ++i)
            gl_lds16(Bbase + k0 + i * rstep, &Bs[buf][(t + 256 * i) * 8]);
    };

    auto compute = [&](int buf) {
#pragma unroll
        for (int s = 0; s < 2; ++s) {
            const int cq = s ? cq1 : cq0;
            bf16x8 af[4], bfr[2];
#pragma unroll
            for (int i = 0; i < 4; ++i)
                af[i] = *(const bf16x8*)(&As[buf][(i * 16 + l16) * 64 + cq]);
#pragma unroll
            for (int j = 0; j < 2; ++j)
                bfr[j] = *(const bf16x8*)(&Bs[buf][(wn + j * 16 + l16) * 64 + cq]);
#pragma unroll
            for (int i = 0; i < 4; ++i)
#pragma unroll
                for (int j = 0; j < 2; ++j)
                    acc[i][j] = __builtin_amdgcn_mfma_f32_16x16x32_bf16(af[i], bfr[j], acc[i][j], 0, 0, 0);
        }
    };

    stage(0, 0);
    __syncthreads();

    for (int k0 = 0; k0 < K; k0 += 128) {
        if (k0 + 64 < K) stage(1, k0 + 64);
        compute(0);
        __syncthreads();
        if (k0 + 128 < K) stage(0, k0 + 128);
        compute(1);
        __syncthreads();
    }

#pragma unroll
    for (int i = 0; i < 4; ++i)
#pragma unroll
        for (int r = 0; r < 4; ++r) {
            long long row = m0 + i * 16 + quad * 4 + r;
#pragma unroll
            for (int j = 0; j < 2; ++j)
                Cout[row * (long long)N + (n0 + wn + j * 16 + l16)] = (bf16)acc[i][j][r];
        }
}

// ----------------------------------------------------------------
extern "C" void kernel_launch(void* const* d_in, const int* in_sizes, int n_in,
                              void* d_out, int out_size, void* d_ws, size_t ws_size,
                              hipStream_t stream) {
    const int B = 8, S = 2048, D = 512;
    const float* x = (const float*)d_in[0];
    const float* W = (const float*)d_in[1];
    float* out = (float*)d_out;

    const size_t nx = (size_t)B * S * D;
    const size_t nw = (size_t)D * D;

    char* ws = (char*)d_ws;
    auto al = [](size_t v) { return (v + 255) & ~(size_t)255; };
    size_t off = 0;
    bf16* xb = (bf16*)(ws + off); off = al(off + nx * 2);          // x bf16 [B,S,D]
    bf16* xt = (bf16*)(ws + off); off = al(off + nx * 2);          // x^T bf16 [B,D,S]
    bf16* pb = (bf16*)(ws + off); off = al(off + nx * 2);          // proj bf16 [B,S,D]
    bf16* wt = (bf16*)(ws + off); off = al(off + nw * 2);          // W^T bf16 [D,D]
    float* rpart = (float*)(ws + off); off = al(off + (size_t)B * S * NSLOT * 4);  // rowsum partials
    bf16* sb = (bf16*)(ws + off);                                  // P_unnorm bf16
    const size_t full_need = off + (size_t)B * S * S * 2;
    const bool batched = (ws_size >= full_need);

    { dim3 g(S / 32, D / 32, B); cast_both<<<g, 256, 0, stream>>>(x, xb, xt, S, D); }
    { dim3 g(D / 32, D / 32, 1); cast_transpose<<<g, 256, 0, stream>>>(W, wt, D, D); }

    // proj: pb[BS,D] = xb @ wt^T   (grid 256x4 = 1024 blocks)
    {
        dim3 g(B * S / 64, D / 128, 1);
        gemm64_nt<<<g, 256, 0, stream>>>(xb, wt, pb, B * S, D, D);
    }

    const long long sd = (long long)S * D;
    const long long ss = (long long)S * S;

    if (batched) {
        // P_un = exp(tanh(pb @ xb^T)), rowsum partials   (grid 8x16x8)
        dim3 g2(S / 256, S / 128, B);
        gemm256<1><<<g2, 512, 0, stream>>>(pb, xb, (void*)sb, rpart, S, S, D, sd, sd, ss, S);
        // out = (P_un @ xt^T) * invRowsum                (grid 8x4x8 = 256 blocks = 1/CU)
        dim3 g4(S / 256, D / 128, B);
        gemm256<2><<<g4, 512, 0, stream>>>(sb, xt, (void*)out, rpart, S, D, S, ss, sd, sd, S);
    } else {
        for (int b = 0; b < B; ++b) {
            dim3 g2(S / 256, S / 128, 1);
            gemm256<1><<<g2, 512, 0, stream>>>(pb + (size_t)b * sd, xb + (size_t)b * sd,
                                               (void*)sb, rpart + (size_t)b * S * NSLOT,
                                               S, S, D, 0, 0, 0, S);
            dim3 g4(S / 256, D / 128, 1);
            gemm256<2><<<g4, 512, 0, stream>>>(sb, xt + (size_t)b * sd,
                                               (void*)(out + (size_t)b * sd), rpart + (size_t)b * S * NSLOT,
                                               S, D, S, 0, 0, 0, S);
        }
    }
}

// Round 3
// 213.981 us; speedup vs baseline: 1.0951x; 1.0951x over previous
//
#include <hip/hip_runtime.h>
#include <hip/hip_bf16.h>

typedef __bf16 bf16;
typedef __attribute__((ext_vector_type(8))) __bf16 bf16x8;
typedef __attribute__((ext_vector_type(4))) float floatx4;

#define NSLOT 32   // rowsum partial slots per row: scores has 8 n-blocks x 4 wave-cols

#define BARM() asm volatile("s_barrier" ::: "memory")

// async global->LDS, 16B per lane: HW dest = wave-uniform base + lane*16.
__device__ __forceinline__ void gl_lds16(const bf16* g, bf16* l) {
    __builtin_amdgcn_global_load_lds(
        (const __attribute__((address_space(1))) unsigned int*)g,
        (__attribute__((address_space(3))) unsigned int*)l,
        16, 0, 0);
}

// supertile swizzle for L2 locality. Requires gridDim.x%4==0, gridDim.y%2==0. Bijective.
__device__ __forceinline__ void swizzle_mn(int& bm, int& bn) {
    int gx = gridDim.x;
    int f  = blockIdx.y * gx + blockIdx.x;
    int st = f >> 3, r = f & 7;
    int mgroups = gx >> 2;
    bm = (st % mgroups) * 4 + (r & 3);
    bn = (st / mgroups) * 2 + (r >> 2);
}

// ---------------------------------------------------------------- x fp32 [R,C] -> xb bf16 [R,C] AND xt bf16 [C,R]
__global__ __launch_bounds__(256) void cast_both(const float* __restrict__ in,
                                                 bf16* __restrict__ outn,
                                                 bf16* __restrict__ outt,
                                                 int R, int C) {
    __shared__ float tile[32][33];
    const long long bz = blockIdx.z;
    in   += bz * (long long)R * C;
    outn += bz * (long long)R * C;
    outt += bz * (long long)R * C;
    const int r0 = blockIdx.x * 32, c0 = blockIdx.y * 32;
    const int tx = threadIdx.x & 31, ty = threadIdx.x >> 5;
#pragma unroll
    for (int i = 0; i < 32; i += 8) {
        float v = in[(long long)(r0 + ty + i) * C + (c0 + tx)];
        tile[ty + i][tx] = v;
        outn[(long long)(r0 + ty + i) * C + (c0 + tx)] = (bf16)v;
    }
    __syncthreads();
#pragma unroll
    for (int i = 0; i < 32; i += 8)
        outt[(long long)(c0 + ty + i) * R + (r0 + tx)] = (bf16)tile[tx][ty + i];
}

// ---------------------------------------------------------------- fp32 [R,C] -> bf16 [C,R] (for W)
__global__ __launch_bounds__(256) void cast_transpose(const float* __restrict__ in,
                                                      bf16* __restrict__ out,
                                                      int R, int C) {
    __shared__ float tile[32][33];
    const int r0 = blockIdx.x * 32, c0 = blockIdx.y * 32;
    const int tx = threadIdx.x & 31, ty = threadIdx.x >> 5;
#pragma unroll
    for (int i = 0; i < 32; i += 8)
        tile[ty + i][tx] = in[(long long)(r0 + ty + i) * C + (c0 + tx)];
    __syncthreads();
#pragma unroll
    for (int i = 0; i < 32; i += 8)
        out[(long long)(c0 + ty + i) * R + (r0 + tx)] = (bf16)tile[tx][ty + i];
}

// tanh via one exp + one rcp; exact saturation at +-1.
__device__ __forceinline__ float fast_tanh(float v) {
    float e = __expf(2.0f * v);
    return 1.0f - 2.0f / (e + 1.0f);
}

// ================================================================ R11: fine-grained phase schedule
// LDS tile layout per matrix: [buf2][khalf2][rows][32] bf16, 16B chunks XOR-swizzled:
//   slot chunk c at row r holds global chunk c ^ ((r>>1)&3).
// Stage unit = one (matrix, khalf): rows x 32 cols. Per gl_lds instruction a wave writes 1KB
// = 16 rows x 32 cols; lane writes row base+(lane>>2), chunk lane&3 from global chunk
// (lane&3)^((lane>>3)&3)  [= c ^ ((row>>1)&3) since row = 16k + (lane>>2)].
// Frag read: lane(q,l16) row ..+l16, slot chunk q ^ ((l16>>1)&3) -> within a 16-lane group each
// 4-bank slot gets 2 even + 2 odd rows (row stride 64B) = 2-way = free (m136).

// ---------------------------------------------------------------- scores: 256x256, 8 waves 2Mx4N, K=512
// C = exp(tanh(A.B^T)) bf16 + per-(row, n-block, wave-col) rowsum partials.
// 4 phases/K-tile: P1(k0,mlo: rdB+rdA8, stage A'k1) P2(k0,mhi: rdA4, stage B'k1, WAIT)
//                  P3(k1,mlo: rdB+rdA8, stage A''k0) P4(k1,mhi: rdA4, stage B''k0, WAIT)
// vmcnt(8): 4 units x 2 loads in flight; lgkmcnt(0) before the end barrier guards the LDS region
// that the next phase's stage overwrites.
__global__ __launch_bounds__(512) void gemm_scores(const bf16* __restrict__ A,
                                                   const bf16* __restrict__ Bm,
                                                   bf16* __restrict__ Cout,
                                                   float* __restrict__ rpart,
                                                   long long batchA, long long batchB,
                                                   long long batchC, long long batchR) {
    constexpr int K = 512, NT = K / 64, N = 2048;
    __shared__ bf16 As[32768];   // 64 KB
    __shared__ bf16 Bs[32768];   // 64 KB

    const long long bz = blockIdx.z;
    A  += bz * batchA;
    Bm += bz * batchB;

    const int t = threadIdx.x, lane = t & 63, w = t >> 6;
    const int quad = lane >> 4, l16 = lane & 15;
    const int wr = w >> 2, wc = w & 3;          // 2 x 4 wave grid
    int bm, bn; swizzle_mn(bm, bn);
    const int m0 = bm * 256, n0 = bn * 256;

    // staging addressing
    const int gch = ((lane & 3) ^ ((lane >> 3) & 3)) * 8;
    const bf16* aSrc = A  + (long long)(m0 + w * 32 + (lane >> 2)) * K + gch;
    const bf16* bSrc = Bm + (long long)(n0 + w * 32 + (lane >> 2)) * K + gch;
    const int ldst = w * 1024 + lane * 8;
    const long long j16K = 16LL * K;
    // frag-read addressing
    const int rdch = (quad ^ ((l16 >> 1) & 3)) * 8;
    const int rA0 = (wr * 128 + l16) * 32 + rdch;
    const int rB0 = (wc * 64 + l16) * 32 + rdch;

    floatx4 accL[4][4] = {}, accH[4][4] = {};
    bf16x8 af[4], bfr[4];

    auto stgA = [&](int kt, int h, int buf) {
        const bf16* s = aSrc + (long long)kt * 64 + h * 32;
        bf16* d = &As[(buf * 2 + h) * 8192 + ldst];
        gl_lds16(s, d); gl_lds16(s + j16K, d + 512);
    };
    auto stgB = [&](int kt, int h, int buf) {
        const bf16* s = bSrc + (long long)kt * 64 + h * 32;
        bf16* d = &Bs[(buf * 2 + h) * 8192 + ldst];
        gl_lds16(s, d); gl_lds16(s + j16K, d + 512);
    };
    auto rdB4 = [&](int p, int h) {
#pragma unroll
        for (int j = 0; j < 4; ++j)
            bfr[j] = *(const bf16x8*)&Bs[(p * 2 + h) * 8192 + rB0 + j * 512];
    };
    auto rdA4 = [&](int p, int h, int mh) {
#pragma unroll
        for (int i = 0; i < 4; ++i)
            af[i] = *(const bf16x8*)&As[(p * 2 + h) * 8192 + rA0 + mh * 2048 + i * 512];
    };
    auto mmL = [&]() {
        __builtin_amdgcn_s_setprio(1);
#pragma unroll
        for (int i = 0; i < 4; ++i)
#pragma unroll
            for (int j = 0; j < 4; ++j)
                accL[i][j] = __builtin_amdgcn_mfma_f32_16x16x32_bf16(af[i], bfr[j], accL[i][j], 0, 0, 0);
        __builtin_amdgcn_s_setprio(0);
    };
    auto mmH = [&]() {
        __builtin_amdgcn_s_setprio(1);
#pragma unroll
        for (int i = 0; i < 4; ++i)
#pragma unroll
            for (int j = 0; j < 4; ++j)
                accH[i][j] = __builtin_amdgcn_mfma_f32_16x16x32_bf16(af[i], bfr[j], accH[i][j], 0, 0, 0);
        __builtin_amdgcn_s_setprio(0);
    };

    // prologue: tile0 complete + tile1 khalf0
    stgA(0, 0, 0); stgB(0, 0, 0); stgA(0, 1, 0); stgB(0, 1, 0); stgA(1, 0, 1); stgB(1, 0, 1);
    asm volatile("s_waitcnt vmcnt(8)" ::: "memory"); BARM();

    for (int kt = 0; kt < NT - 2; ++kt) {
        const int p = kt & 1, q = p ^ 1;
        rdB4(p, 0); rdA4(p, 0, 0); stgA(kt + 1, 1, q);
        BARM(); mmL(); BARM();
        rdA4(p, 0, 1); stgB(kt + 1, 1, q);
        BARM(); mmH();
        asm volatile("s_waitcnt vmcnt(8) lgkmcnt(0)" ::: "memory"); BARM();
        rdB4(p, 1); rdA4(p, 1, 0); stgA(kt + 2, 0, p);
        BARM(); mmL(); BARM();
        rdA4(p, 1, 1); stgB(kt + 2, 0, p);
        BARM(); mmH();
        asm volatile("s_waitcnt vmcnt(8) lgkmcnt(0)" ::: "memory"); BARM();
    }
    {   // kt = NT-2: no kt+2 stages; P4 wait drops to 4
        const int p = (NT - 2) & 1, q = p ^ 1;
        rdB4(p, 0); rdA4(p, 0, 0); stgA(NT - 1, 1, q);
        BARM(); mmL(); BARM();
        rdA4(p, 0, 1); stgB(NT - 1, 1, q);
        BARM(); mmH();
        asm volatile("s_waitcnt vmcnt(8) lgkmcnt(0)" ::: "memory"); BARM();
        rdB4(p, 1); rdA4(p, 1, 0);
        BARM(); mmL(); BARM();
        rdA4(p, 1, 1);
        BARM(); mmH();
        asm volatile("s_waitcnt vmcnt(4) lgkmcnt(0)" ::: "memory"); BARM();
    }
    {   // kt = NT-1: final tile, drain at P2 end only
        const int p = (NT - 1) & 1;
        rdB4(p, 0); rdA4(p, 0, 0);
        BARM(); mmL(); BARM();
        rdA4(p, 0, 1);
        BARM(); mmH();
        asm volatile("s_waitcnt vmcnt(0) lgkmcnt(0)" ::: "memory"); BARM();
        rdB4(p, 1); rdA4(p, 1, 0);
        BARM(); mmL(); BARM();
        rdA4(p, 1, 1);
        BARM(); mmH();
    }

    // epilogue: exp(tanh(.)), bf16 store, rowsum partials (slot private per (n-block, wave-col))
    bf16* Cg = Cout + bz * batchC;
    const int slot = bn * 4 + wc;
#define EPI(ACC, MH)                                                                  \
    _Pragma("unroll") for (int i = 0; i < 4; ++i)                                     \
    _Pragma("unroll") for (int r = 0; r < 4; ++r) {                                   \
        long long row = m0 + wr * 128 + (MH) * 64 + i * 16 + quad * 4 + r;            \
        float s = 0.f;                                                                \
        _Pragma("unroll") for (int j = 0; j < 4; ++j) {                               \
            float v = __expf(fast_tanh(ACC[i][j][r]));                                \
            s += v;                                                                   \
            Cg[row * (long long)N + (n0 + wc * 64 + j * 16 + l16)] = (bf16)v;         \
        }                                                                             \
        _Pragma("unroll") for (int msk = 1; msk < 16; msk <<= 1) s += __shfl_xor(s, msk); \
        if (l16 == 0) rpart[(bz * batchR + row) * NSLOT + slot] = s;                  \
    }
    EPI(accL, 0)
    EPI(accH, 1)
#undef EPI
}

// ---------------------------------------------------------------- PV: 256x128, 8 waves 4Mx2N, K=2048
// out = (P_un . xt^T) * invRowsum, fp32. 2 phases/K-tile (k-halves); 3 loads staged per phase;
// vmcnt(6) lgkmcnt(0) + barrier at every phase end.
__global__ __launch_bounds__(512) void gemm_pv(const bf16* __restrict__ A,
                                               const bf16* __restrict__ Bm,
                                               float* __restrict__ Out,
                                               const float* __restrict__ rpart,
                                               long long batchA, long long batchB,
                                               long long batchC, long long batchR) {
    constexpr int K = 2048, NT = K / 64, N = 512;
    __shared__ bf16 As[32768];   // 64 KB [buf][half][256][32]
    __shared__ bf16 Bs[16384];   // 32 KB [buf][half][128][32]
    __shared__ float rs[256];

    const long long bz = blockIdx.z;
    A  += bz * batchA;
    Bm += bz * batchB;

    const int t = threadIdx.x, lane = t & 63, w = t >> 6;
    const int quad = lane >> 4, l16 = lane & 15;
    const int wr = w >> 1, wc = w & 1;          // 4 x 2 wave grid
    int bm, bn; swizzle_mn(bm, bn);
    const int m0 = bm * 256, n0 = bn * 128;

    // softmax denominators (loads fully retired before fence -> vmcnt ledger below stays exact)
    if (t < 256) {
        const float* pp = rpart + (bz * batchR + m0 + t) * NSLOT;
        float s = 0.f;
#pragma unroll
        for (int c = 0; c < NSLOT / 4; ++c) {
            float4 p4 = ((const float4*)pp)[c];
            s += (p4.x + p4.y) + (p4.z + p4.w);
        }
        rs[t] = 1.0f / s;
    }
    asm volatile("" ::: "memory");

    const int gch = ((lane & 3) ^ ((lane >> 3) & 3)) * 8;
    const bf16* aSrc = A  + (long long)(m0 + w * 32 + (lane >> 2)) * K + gch;
    const bf16* bSrc = Bm + (long long)(n0 + w * 16 + (lane >> 2)) * K + gch;
    const int ldstA = w * 1024 + lane * 8;
    const int ldstB = w * 512 + lane * 8;
    const long long j16K = 16LL * K;
    const int rdch = (quad ^ ((l16 >> 1) & 3)) * 8;
    const int rA0 = (wr * 64 + l16) * 32 + rdch;
    const int rB0 = (wc * 64 + l16) * 32 + rdch;

    floatx4 acc[4][4] = {};
    bf16x8 af[4], bfr[4];

    auto stgA = [&](int kt, int h, int buf) {
        const bf16* s = aSrc + (long long)kt * 64 + h * 32;
        bf16* d = &As[(buf * 2 + h) * 8192 + ldstA];
        gl_lds16(s, d); gl_lds16(s + j16K, d + 512);
    };
    auto stgB = [&](int kt, int h, int buf) {
        gl_lds16(bSrc + (long long)kt * 64 + h * 32, &Bs[(buf * 2 + h) * 4096 + ldstB]);
    };
    auto rd8 = [&](int p, int h) {
#pragma unroll
        for (int i = 0; i < 4; ++i)
            af[i] = *(const bf16x8*)&As[(p * 2 + h) * 8192 + rA0 + i * 512];
#pragma unroll
        for (int j = 0; j < 4; ++j)
            bfr[j] = *(const bf16x8*)&Bs[(p * 2 + h) * 4096 + rB0 + j * 512];
    };
    auto mm16 = [&]() {
        __builtin_amdgcn_s_setprio(1);
#pragma unroll
        for (int i = 0; i < 4; ++i)
#pragma unroll
            for (int j = 0; j < 4; ++j)
                acc[i][j] = __builtin_amdgcn_mfma_f32_16x16x32_bf16(af[i], bfr[j], acc[i][j], 0, 0, 0);
        __builtin_amdgcn_s_setprio(0);
    };

    // prologue: tile0 complete + tile1 khalf0 (wait leaves tile1-k0's 3 loads in flight)
    stgA(0, 0, 0); stgB(0, 0, 0); stgA(0, 1, 0); stgB(0, 1, 0); stgA(1, 0, 1); stgB(1, 0, 1);
    asm volatile("s_waitcnt vmcnt(3)" ::: "memory"); BARM();

    for (int kt = 0; kt < NT - 2; ++kt) {
        const int p = kt & 1, q = p ^ 1;
        rd8(p, 0); stgA(kt + 1, 1, q); stgB(kt + 1, 1, q);
        BARM(); mm16();
        asm volatile("s_waitcnt vmcnt(6) lgkmcnt(0)" ::: "memory"); BARM();
        rd8(p, 1); stgA(kt + 2, 0, p); stgB(kt + 2, 0, p);
        BARM(); mm16();
        asm volatile("s_waitcnt vmcnt(6) lgkmcnt(0)" ::: "memory"); BARM();
    }
    {   // kt = NT-2
        const int p = (NT - 2) & 1, q = p ^ 1;
        rd8(p, 0); stgA(NT - 1, 1, q); stgB(NT - 1, 1, q);
        BARM(); mm16();
        asm volatile("s_waitcnt vmcnt(6) lgkmcnt(0)" ::: "memory"); BARM();
        rd8(p, 1);
        BARM(); mm16();
        asm volatile("s_waitcnt vmcnt(3) lgkmcnt(0)" ::: "memory"); BARM();
    }
    {   // kt = NT-1
        const int p = (NT - 1) & 1;
        rd8(p, 0);
        BARM(); mm16();
        asm volatile("s_waitcnt vmcnt(0) lgkmcnt(0)" ::: "memory"); BARM();
        rd8(p, 1);
        BARM(); mm16();
    }

    float* Og = Out + bz * batchC;
#pragma unroll
    for (int i = 0; i < 4; ++i)
#pragma unroll
        for (int r = 0; r < 4; ++r) {
            int rl = wr * 64 + i * 16 + quad * 4 + r;
            float inv = rs[rl];
            long long row = m0 + rl;
#pragma unroll
            for (int j = 0; j < 4; ++j)
                Og[row * (long long)N + (n0 + wc * 64 + j * 16 + l16)] = acc[i][j][r] * inv;
        }
}

// ---------------------------------------------------------------- 64(M)x128(N) tile, BK=64, NT (proj)
// 2-phase double-buffered (R9); small kernel, unchanged this round.
__global__ __launch_bounds__(256) void gemm64_nt(const bf16* __restrict__ A,
                                                 const bf16* __restrict__ Bm,
                                                 bf16* __restrict__ Cout,
                                                 int M, int N, int K) {
    __shared__ bf16 As[2][64 * 64];
    __shared__ bf16 Bs[2][128 * 64];

    const int t    = threadIdx.x;
    const int lane = t & 63;
    const int wave = t >> 6;
    const int quad = lane >> 4;
    const int l16  = lane & 15;

    const int m0 = blockIdx.x * 64;
    const int n0 = blockIdx.y * 128;
    const int wn = wave * 32;

    floatx4 acc[4][2] = {};

    const int ra = t >> 3;
    const int ca = (((t & 7) ^ (ra & 7))) * 8;
    const long long rstep = 32LL * K;
    const bf16* Abase = A + (long long)(m0 + ra) * K + ca;
    const bf16* Bbase = Bm + (long long)(n0 + ra) * K + ca;

    const int cq0 = ((quad) ^ (l16 & 7)) * 8;
    const int cq1 = ((4 + quad) ^ (l16 & 7)) * 8;

    auto stage = [&](int buf, int k0) {
#pragma unroll
        for (int i = 0; i < 2; ++i)
            gl_lds16(Abase + k0 + i * rstep, &As[buf][(t + 256 * i) * 8]);
#pragma unroll
        for (int i = 0; i < 4; ++i)
            gl_lds16(Bbase + k0 + i * rstep, &Bs[buf][(t + 256 * i) * 8]);
    };

    auto compute = [&](int buf) {
#pragma unroll
        for (int s = 0; s < 2; ++s) {
            const int cq = s ? cq1 : cq0;
            bf16x8 af[4], bfr[2];
#pragma unroll
            for (int i = 0; i < 4; ++i)
                af[i] = *(const bf16x8*)(&As[buf][(i * 16 + l16) * 64 + cq]);
#pragma unroll
            for (int j = 0; j < 2; ++j)
                bfr[j] = *(const bf16x8*)(&Bs[buf][(wn + j * 16 + l16) * 64 + cq]);
#pragma unroll
            for (int i = 0; i < 4; ++i)
#pragma unroll
                for (int j = 0; j < 2; ++j)
                    acc[i][j] = __builtin_amdgcn_mfma_f32_16x16x32_bf16(af[i], bfr[j], acc[i][j], 0, 0, 0);
        }
    };

    stage(0, 0);
    __syncthreads();

    for (int k0 = 0; k0 < K; k0 += 128) {
        if (k0 + 64 < K) stage(1, k0 + 64);
        compute(0);
        __syncthreads();
        if (k0 + 128 < K) stage(0, k0 + 128);
        compute(1);
        __syncthreads();
    }

#pragma unroll
    for (int i = 0; i < 4; ++i)
#pragma unroll
        for (int r = 0; r < 4; ++r) {
            long long row = m0 + i * 16 + quad * 4 + r;
#pragma unroll
            for (int j = 0; j < 2; ++j)
                Cout[row * (long long)N + (n0 + wn + j * 16 + l16)] = (bf16)acc[i][j][r];
        }
}

// ----------------------------------------------------------------
extern "C" void kernel_launch(void* const* d_in, const int* in_sizes, int n_in,
                              void* d_out, int out_size, void* d_ws, size_t ws_size,
                              hipStream_t stream) {
    const int B = 8, S = 2048, D = 512;
    const float* x = (const float*)d_in[0];
    const float* W = (const float*)d_in[1];
    float* out = (float*)d_out;

    const size_t nx = (size_t)B * S * D;
    const size_t nw = (size_t)D * D;

    char* ws = (char*)d_ws;
    auto al = [](size_t v) { return (v + 255) & ~(size_t)255; };
    size_t off = 0;
    bf16* xb = (bf16*)(ws + off); off = al(off + nx * 2);          // x bf16 [B,S,D]
    bf16* xt = (bf16*)(ws + off); off = al(off + nx * 2);          // x^T bf16 [B,D,S]
    bf16* pb = (bf16*)(ws + off); off = al(off + nx * 2);          // proj bf16 [B,S,D]
    bf16* wt = (bf16*)(ws + off); off = al(off + nw * 2);          // W^T bf16 [D,D]
    float* rpart = (float*)(ws + off); off = al(off + (size_t)B * S * NSLOT * 4);
    bf16* sb = (bf16*)(ws + off);                                  // P_unnorm bf16
    const size_t full_need = off + (size_t)B * S * S * 2;
    const bool batched = (ws_size >= full_need);

    { dim3 g(S / 32, D / 32, B); cast_both<<<g, 256, 0, stream>>>(x, xb, xt, S, D); }
    { dim3 g(D / 32, D / 32, 1); cast_transpose<<<g, 256, 0, stream>>>(W, wt, D, D); }

    // proj: pb[BS,D] = xb @ wt^T
    {
        dim3 g(B * S / 64, D / 128, 1);
        gemm64_nt<<<g, 256, 0, stream>>>(xb, wt, pb, B * S, D, D);
    }

    const long long sd = (long long)S * D;
    const long long ss = (long long)S * S;

    if (batched) {
        dim3 g2(S / 256, S / 256, B);   // 8x8x8
        gemm_scores<<<g2, 512, 0, stream>>>(pb, xb, sb, rpart, sd, sd, ss, S);
        dim3 g4(S / 256, D / 128, B);   // 8x4x8 = 256 blocks = 1/CU
        gemm_pv<<<g4, 512, 0, stream>>>(sb, xt, out, rpart, ss, sd, sd, S);
    } else {
        for (int b = 0; b < B; ++b) {
            dim3 g2(S / 256, S / 256, 1);
            gemm_scores<<<g2, 512, 0, stream>>>(pb + (size_t)b * sd, xb + (size_t)b * sd,
                                                sb, rpart + (size_t)b * S * NSLOT, 0, 0, 0, S);
            dim3 g4(S / 256, D / 128, 1);
            gemm_pv<<<g4, 512, 0, stream>>>(sb, xt + (size_t)b * sd,
                                            out + (size_t)b * sd, rpart + (size_t)b * S * NSLOT,
                                            0, 0, 0, S);
        }
    }
}